// Round 8
// baseline (650.075 us; speedup 1.0000x reference)
//
#include <hip/hip_runtime.h>
#include <hip/hip_bf16.h>

// ============================================================================
// Hybrid matrix prefix scan:  res[k] = x @ (m_0 ... m_{k-1}),  N=1024, D=256.
// Deviation form everywhere: store P - I in bf16; combine is exact:
//   dev(XY) = devX + devY + devX@devY.
// Round 11: PARITY-TRANSPOSED intermediate storage.
//   Every intermediate mat is consumed exactly once at the next level: even
//   index -> A operand (wants row-major), odd index -> B operand (wants
//   col-major). So producers write odd-index outputs TRANSPOSED (same
//   buffers, no extra traffic), and the bf16 levels' B-fragments become
//   direct contiguous short8 register loads -- no staging LDS, no transpose
//   gather, no barrier before the C-restage. New kernel gemm_bt (levels 2-7).
//   Level-1 keeps the proven 565us fp32 body verbatim + parity-store branch.
//   Tail branches per-mat on parity (identical fp op order). Narrow path and
//   fallback unchanged (flags 0 -> old behavior).
// ============================================================================

#define D 256
#define DD 65536

typedef __attribute__((ext_vector_type(8))) short short8;
typedef __attribute__((ext_vector_type(4))) float f4;

__device__ __forceinline__ float bf2f(unsigned short u) {
  return __uint_as_float(((unsigned)u) << 16);
}
__device__ __forceinline__ unsigned short f2bf(float f) {
  __hip_bfloat16 h = __float2bfloat16(f);
  unsigned short u;
  __builtin_memcpy(&u, &h, 2);
  return u;
}
__device__ __forceinline__ unsigned f2bf2(float lo, float hi) {
  __hip_bfloat162 h = __float22bfloat162_rn(make_float2(lo, hi));
  unsigned u;
  __builtin_memcpy(&u, &h, 4);
  return u;
}
// fragment-order slot lane index: frag reads lane-contiguous b128.
#define LSWZ(i15, lq) (((((i15) & 15)) + ((lq) << 4)) ^ (lq))

// out[mat] = devA + devB + devA@devB (bf16 dev out), MFMA 16x16x32 bf16.
// 64x64 tile/block (16 blocks/mat), 4 waves. B staged full-K in LDS (32 KiB);
// A fragments live in registers. Block swizzle: xcd = bx&7.
// wTodd: if set, odd-index output mats are stored TRANSPOSED.
__global__ __launch_bounds__(256, 4) void gemm_mfma(
    const float* __restrict__ aF, const unsigned short* __restrict__ aBf,
    long aMul, long aOff,
    const float* __restrict__ bF, const unsigned short* __restrict__ bBf,
    long bMul, long bOff,
    unsigned short* __restrict__ out, int wTodd)
{
  __shared__ __attribute__((aligned(16))) unsigned short Bs[16384]; // 32 KiB

  const int  bx  = blockIdx.x;
  const int  nmb = ((int)gridDim.x) >> 4;         // mats this dispatch (mult of 8)
  const int  xcd = bx & 7, q = bx >> 3;
  const long mat = (long)(xcd * (nmb >> 3)) + (q >> 4);
  const int  tile = q & 15;
  const int  m0 = (tile >> 2) << 6, n0 = (tile & 3) << 6;
  const long aBase = (mat * aMul + aOff) * (long)DD;
  const long bBase = (mat * bMul + bOff) * (long)DD;
  const int t = threadIdx.x;
  const int w = t >> 6, l = t & 63, lm = l & 15, lq4 = l >> 4;
  const int lswz = l ^ lq4;

  // ---- A fragments straight to registers.
  const int R = m0 + (w << 4) + lm;
  short8 areg[8];
  if (aF) {
    const float* ap = aF + aBase + (long)R * D + (lq4 << 3);
#pragma unroll
    for (int kt = 0; kt < 8; ++kt) {
      float4 v0 = *(const float4*)(ap + (kt << 5));
      float4 v1 = *(const float4*)(ap + (kt << 5) + 4);
      if ((R >> 3) == (kt << 2) + lq4) {          // diag fixup (one strip)
        const int j = R & 7;
        if      (j == 0) v0.x -= 1.f;
        else if (j == 1) v0.y -= 1.f;
        else if (j == 2) v0.z -= 1.f;
        else if (j == 3) v0.w -= 1.f;
        else if (j == 4) v1.x -= 1.f;
        else if (j == 5) v1.y -= 1.f;
        else if (j == 6) v1.z -= 1.f;
        else             v1.w -= 1.f;
      }
      union { short8 v8; unsigned u[4]; } ou;
      ou.u[0] = f2bf2(v0.x, v0.y);
      ou.u[1] = f2bf2(v0.z, v0.w);
      ou.u[2] = f2bf2(v1.x, v1.y);
      ou.u[3] = f2bf2(v1.z, v1.w);
      areg[kt] = ou.v8;
    }
  } else {
    const unsigned short* ap = aBf + aBase + (long)R * D + (lq4 << 3);
#pragma unroll
    for (int kt = 0; kt < 8; ++kt)
      areg[kt] = *(const short8*)(ap + (kt << 5));
  }

  // ---- stage B cols [n0,n0+64) x k[0,256) (register transpose into LDS)
  {
    const int n4 = (t & 15) << 2;
    const int kb0 = (t >> 4) << 3;
    const int gn = n0 + n4;
#pragma unroll
    for (int kp = 0; kp < 2; ++kp) {
      const int k8 = kb0 + (kp << 7);
      const int lq = (k8 >> 3) & 3, kt = k8 >> 5;
      if (bF) {
        unsigned tmpu[4][4];
        const int rel = gn - k8;
#pragma unroll
        for (int h = 0; h < 2; ++h) {
          float4 va[2], vb[2];
#pragma unroll
          for (int p2 = 0; p2 < 2; ++p2) {
            va[p2] = *(const float4*)(bF + bBase + (long)(k8 + 4 * h + 2 * p2) * D + gn);
            vb[p2] = *(const float4*)(bF + bBase + (long)(k8 + 4 * h + 2 * p2 + 1) * D + gn);
          }
          if (rel == 4 * h) {
            va[0].x -= 1.f; vb[0].y -= 1.f; va[1].z -= 1.f; vb[1].w -= 1.f;
          }
          tmpu[0][2 * h + 0] = f2bf2(va[0].x, vb[0].x);
          tmpu[0][2 * h + 1] = f2bf2(va[1].x, vb[1].x);
          tmpu[1][2 * h + 0] = f2bf2(va[0].y, vb[0].y);
          tmpu[1][2 * h + 1] = f2bf2(va[1].y, vb[1].y);
          tmpu[2][2 * h + 0] = f2bf2(va[0].z, vb[0].z);
          tmpu[2][2 * h + 1] = f2bf2(va[1].z, vb[1].z);
          tmpu[3][2 * h + 0] = f2bf2(va[0].w, vb[0].w);
          tmpu[3][2 * h + 1] = f2bf2(va[1].w, vb[1].w);
        }
#pragma unroll
        for (int jj = 0; jj < 4; ++jj) {
          const int n = n4 + jj;
          const int slot = (((n >> 4) << 3) + kt) * 64 + LSWZ(n, lq);
          uint4 st = { tmpu[jj][0], tmpu[jj][1], tmpu[jj][2], tmpu[jj][3] };
          *(uint4*)&Bs[slot << 3] = st;
        }
      } else {
        __attribute__((aligned(16))) unsigned short tmp[4][8];
#pragma unroll
        for (int kk = 0; kk < 8; ++kk) {
          const ushort4 v = *(const ushort4*)(bBf + bBase + (long)(k8 + kk) * D + gn);
          tmp[0][kk] = v.x; tmp[1][kk] = v.y; tmp[2][kk] = v.z; tmp[3][kk] = v.w;
        }
#pragma unroll
        for (int jj = 0; jj < 4; ++jj) {
          const int n = n4 + jj;
          const int slot = (((n >> 4) << 3) + kt) * 64 + LSWZ(n, lq);
          *(uint4*)&Bs[slot << 3] = *(const uint4*)&tmp[jj][0];
        }
      }
    }
  }
  __syncthreads();

  // ---- MFMA: A from registers, B frags lane-contiguous from LDS (32 b128)
  f4 acc[4] = {{0.f,0.f,0.f,0.f},{0.f,0.f,0.f,0.f},
               {0.f,0.f,0.f,0.f},{0.f,0.f,0.f,0.f}};
#pragma unroll
  for (int kt = 0; kt < 8; ++kt) {
#pragma unroll
    for (int f = 0; f < 4; ++f) {
      const short8 b = *(const short8*)&Bs[((((f << 3) + kt) << 6) + lswz) << 3];
      acc[f] = __builtin_amdgcn_mfma_f32_16x16x32_bf16(areg[kt], b, acc[f], 0, 0, 0);
    }
  }

  // ---- epilogue: s = acc + devA (global re-read, L2-hot) + devB (LDS)
#pragma unroll
  for (int f = 0; f < 4; ++f) {
    const int gj_l = (f << 4) + lm;
    const int gj   = n0 + gj_l;
#pragma unroll
    for (int r = 0; r < 4; ++r) {
      const int gi_l = (w << 4) + (lq4 << 2) + r;
      const int giG  = m0 + gi_l;
      float da;
      if (aF)
        da = aF[aBase + (long)giG * D + gj] - ((giG == gj) ? 1.f : 0.f);
      else
        da = bf2f(aBf[aBase + (long)giG * D + gj]);
      const int lqB  = (giG >> 3) & 3;
      const int slotB = (((gj_l >> 4) << 3) + (giG >> 5)) * 64 + LSWZ(gj_l, lqB);
      const float db = bf2f(Bs[(slotB << 3) + (giG & 7)]);
      acc[f][r] += da + db;
    }
  }
  __syncthreads();                                // all Bs reads done

  // ---- C restage (pitch 66) then coalesced store; wT -> transposed layout
  const int wT = wTodd & (int)(mat & 1);
  unsigned short* Cs = Bs;
#pragma unroll
  for (int f = 0; f < 4; ++f)
#pragma unroll
    for (int r = 0; r < 4; ++r) {
      const int row_ = (w << 4) + (lq4 << 2) + r, col_ = (f << 4) + lm;
      Cs[wT ? (col_ * 66 + row_) : (row_ * 66 + col_)] = f2bf(acc[f][r]);
    }
  __syncthreads();
  {
    const int row = t >> 2, c0g = (t & 3) << 4;
    const unsigned int* Cw = (const unsigned int*)Cs;
    const int wb = row * 33 + ((t & 3) << 3);
    unsigned int wbuf[8];
#pragma unroll
    for (int i = 0; i < 8; ++i) wbuf[i] = Cw[wb + i];
    unsigned short* og = out + mat * (long)DD +
        (wT ? ((long)(n0 + row) * D + m0 + c0g)
            : ((long)(m0 + row) * D + n0 + c0g));
    uint4 o0 = { wbuf[0], wbuf[1], wbuf[2], wbuf[3] };
    uint4 o1 = { wbuf[4], wbuf[5], wbuf[6], wbuf[7] };
    *(uint4*)og = o0;
    *((uint4*)og + 1) = o1;
  }
}

// bf16 levels with parity-transposed inputs: A = in[2*mat] (row-major),
// B = in[2*mat+1] (TRANSPOSED: storage[c*D+r] = devB[r][c]). B-frags are
// direct contiguous short8 loads -> no staging LDS, no barrier before the
// C-restage. wTodd: odd-index outputs stored transposed.
__global__ __launch_bounds__(256, 4) void gemm_bt(
    const unsigned short* __restrict__ in, unsigned short* __restrict__ out,
    int wTodd)
{
  __shared__ __attribute__((aligned(16))) unsigned short Cs[4224]; // 8.25 KiB

  const int  bx  = blockIdx.x;
  const int  nmb = ((int)gridDim.x) >> 4;
  const int  xcd = bx & 7, q = bx >> 3;
  const long mat = (long)(xcd * (nmb >> 3)) + (q >> 4);
  const int  tile = q & 15;
  const int  m0 = (tile >> 2) << 6, n0 = (tile & 3) << 6;
  const unsigned short* aBf = in + 2 * mat * (long)DD;
  const unsigned short* bt  = in + (2 * mat + 1) * (long)DD;
  const int t = threadIdx.x;
  const int w = t >> 6, l = t & 63, lm = l & 15, lq4 = l >> 4;

  // A frags (row-major even mat): lane = row R, k-contiguous
  const int R = m0 + (w << 4) + lm;
  short8 areg[8];
  const unsigned short* ap = aBf + (long)R * D + (lq4 << 3);
#pragma unroll
  for (int kt = 0; kt < 8; ++kt)
    areg[kt] = *(const short8*)(ap + (kt << 5));

  // B frags direct from transposed mat: col = n0+f*16+lm, k-contiguous
  f4 acc[4] = {{0.f,0.f,0.f,0.f},{0.f,0.f,0.f,0.f},
               {0.f,0.f,0.f,0.f},{0.f,0.f,0.f,0.f}};
  const unsigned short* bp = bt + (long)(n0 + lm) * D + (lq4 << 3);
#pragma unroll
  for (int kt = 0; kt < 8; ++kt) {
#pragma unroll
    for (int f = 0; f < 4; ++f) {
      const short8 b = *(const short8*)(bp + ((long)(f << 4)) * D + (kt << 5));
      acc[f] = __builtin_amdgcn_mfma_f32_16x16x32_bf16(areg[kt], b, acc[f], 0, 0, 0);
    }
  }

  // epilogue: + devA (row-major) + devB (transposed), both L2-hot
#pragma unroll
  for (int f = 0; f < 4; ++f) {
    const int gj = n0 + (f << 4) + lm;
#pragma unroll
    for (int r = 0; r < 4; ++r) {
      const int giG = m0 + (w << 4) + (lq4 << 2) + r;
      acc[f][r] += bf2f(aBf[(long)giG * D + gj]) + bf2f(bt[(long)gj * D + giG]);
    }
  }

  // C restage (pitch 66, conflict-free both orientations) + coalesced store
  const int wT = wTodd & (int)(mat & 1);
#pragma unroll
  for (int f = 0; f < 4; ++f)
#pragma unroll
    for (int r = 0; r < 4; ++r) {
      const int row_ = (w << 4) + (lq4 << 2) + r, col_ = (f << 4) + lm;
      Cs[wT ? (col_ * 66 + row_) : (row_ * 66 + col_)] = f2bf(acc[f][r]);
    }
  __syncthreads();
  {
    const int row = t >> 2, c0g = (t & 3) << 4;
    const unsigned int* Cw = (const unsigned int*)Cs;
    const int wb = row * 33 + ((t & 3) << 3);
    unsigned int wbuf[8];
#pragma unroll
    for (int i = 0; i < 8; ++i) wbuf[i] = Cw[wb + i];
    unsigned short* og = out + mat * (long)DD +
        (wT ? ((long)(n0 + row) * D + m0 + c0g)
            : ((long)(m0 + row) * D + n0 + c0g));
    uint4 o0 = { wbuf[0], wbuf[1], wbuf[2], wbuf[3] };
    uint4 o1 = { wbuf[4], wbuf[5], wbuf[6], wbuf[7] };
    *(uint4*)og = o0;
    *((uint4*)og + 1) = o1;
  }
}

// v = v + v @ dev(M), row-major M: 64 col-groups (4 cols) x 16 k-groups.
__device__ __forceinline__ void apply_bf16(const unsigned short* __restrict__ Mb,
                                           float* v, float (*ps)[D],
                                           int t, int col4, int q) {
  const unsigned short* Mp = Mb + (long)(q * 16) * D + col4;
  float a0 = 0.f, a1 = 0.f, a2 = 0.f, a3 = 0.f;
#pragma unroll
  for (int i = 0; i < 16; ++i) {
    const ushort4 u = *(const ushort4*)(Mp + (long)i * D);
    const float vi = v[q * 16 + i];
    a0 += vi * bf2f(u.x); a1 += vi * bf2f(u.y);
    a2 += vi * bf2f(u.z); a3 += vi * bf2f(u.w);
  }
  *(float4*)&ps[q][col4] = make_float4(a0, a1, a2, a3);
  __syncthreads();
  if (t < D) {
    float s = 0.f;
#pragma unroll
    for (int j = 0; j < 16; ++j) s += ps[j][t];
    v[t] += s;
  }
  __syncthreads();
}

// Same, transposed storage (Mt[c*D+r] = M[r][c]); identical fp op order.
__device__ __forceinline__ void apply_bf16_t(const unsigned short* __restrict__ Mt,
                                             float* v, float (*ps)[D],
                                             int t, int col4, int q) {
  float a[4];
#pragma unroll
  for (int j = 0; j < 4; ++j) {
    const unsigned short* p = Mt + (long)(col4 + j) * D + q * 16;
    const short8 u0 = *(const short8*)p;
    const short8 u1 = *(const short8*)(p + 8);
    float s = 0.f;
#pragma unroll
    for (int i = 0; i < 8; ++i)
      s += v[q * 16 + i] * bf2f((unsigned short)u0[i]);
#pragma unroll
    for (int i = 0; i < 8; ++i)
      s += v[q * 16 + 8 + i] * bf2f((unsigned short)u1[i]);
    a[j] = s;
  }
  *(float4*)&ps[q][col4] = make_float4(a[0], a[1], a[2], a[3]);
  __syncthreads();
  if (t < D) {
    float s = 0.f;
#pragma unroll
    for (int j = 0; j < 16; ++j) s += ps[j][t];
    v[t] += s;
  }
  __syncthreads();
}

// ONE kernel for the whole tail. WG c targets prefix length L = 4c:
// greedy span descent (128*,64,32,16,8,4), then exact fp32 bottom mat-vecs.
// trOdd: odd-index span mats (except sp128) are stored transposed.
__global__ __launch_bounds__(1024) void tail_fused(
    const float* __restrict__ x,
    const unsigned short* __restrict__ sp128, const unsigned short* __restrict__ sp64,
    const unsigned short* __restrict__ sp32,  const unsigned short* __restrict__ sp16,
    const unsigned short* __restrict__ sp8,   const unsigned short* __restrict__ sp4,
    const float* __restrict__ m, float* __restrict__ out, int trOdd)
{
  __shared__ float v[D];
  __shared__ float ps[16][D];
  const int c = blockIdx.x, t = threadIdx.x;
  const int col4 = (t & 63) << 2, q = t >> 6;     // 64 col-groups x 16 k-groups
  if (t < D) v[t] = x[t];
  __syncthreads();
  const int L = c << 2;

#define APPLY_P(base, idx)                                              \
  do {                                                                  \
    if (trOdd && (((idx) & 1) != 0))                                    \
      apply_bf16_t((base) + (long)(idx) * DD, v, ps, t, col4, q);       \
    else                                                                \
      apply_bf16((base) + (long)(idx) * DD, v, ps, t, col4, q);         \
  } while (0)

  int pos = 0;
#pragma unroll 1
  while (pos + 128 <= L) {                        // sp128 always row-major
    apply_bf16(sp128 + (long)(pos >> 7) * DD, v, ps, t, col4, q); pos += 128;
  }
  if (pos + 64 <= L) { APPLY_P(sp64, pos >> 6); pos += 64; }
  if (pos + 32 <= L) { APPLY_P(sp32, pos >> 5); pos += 32; }
  if (pos + 16 <= L) { APPLY_P(sp16, pos >> 4); pos += 16; }
  if (pos + 8 <= L)  { APPLY_P(sp8,  pos >> 3); pos += 8; }
  if (pos + 4 <= L)  { APPLY_P(sp4,  pos >> 2); pos += 4; }
#undef APPLY_P

  // bottom: emit rows with exact fp32 mat-vecs over m (float4 loads)
  if (t < D) out[(long)L * D + t] = v[t];
  const int steps = (c == 255) ? 4 : 3;
#pragma unroll 1
  for (int s = 0; s < steps; ++s) {
    const float* Mp = m + (long)(L + s) * DD + (long)(q * 16) * D + col4;
    float a0 = 0.f, a1 = 0.f, a2 = 0.f, a3 = 0.f;
#pragma unroll
    for (int i = 0; i < 16; ++i) {
      const float4 u = *(const float4*)(Mp + (long)i * D);
      const float vi = v[q * 16 + i];
      a0 += vi * u.x; a1 += vi * u.y; a2 += vi * u.z; a3 += vi * u.w;
    }
    *(float4*)&ps[q][col4] = make_float4(a0, a1, a2, a3);
    __syncthreads();
    if (t < D) {
      float s2 = 0.f;
#pragma unroll
      for (int j = 0; j < 16; ++j) s2 += ps[j][t];
      v[t] = s2;
      out[(long)(L + s + 1) * D + t] = s2;
    }
    __syncthreads();
  }
}

// correctness-only fallback if ws is too small: fully sequential chain
__global__ __launch_bounds__(256) void fallback_seq(
    const float* __restrict__ x, const float* __restrict__ m,
    float* __restrict__ out)
{
  __shared__ float v[D];
  const int t = threadIdx.x;
  v[t] = x[t];
  __syncthreads();
  for (int k = 0; k < 1024; ++k) {
    out[(long)k * D + t] = v[t];
    const float* M = m + (long)k * DD;
    float acc = 0.f;
    for (int i = 0; i < D; ++i) acc += v[i] * M[(long)i * D + t];
    __syncthreads();
    v[t] = acc;
    __syncthreads();
  }
  out[(long)1024 * D + t] = v[t];
}

extern "C" void kernel_launch(void* const* d_in, const int* in_sizes, int n_in,
                              void* d_out, int out_size, void* d_ws, size_t ws_size,
                              hipStream_t stream) {
  const float* x = (const float*)d_in[0];   // [1,256] fp32
  const float* m = (const float*)d_in[1];   // [1024,256,256] fp32
  float* out = (float*)d_out;               // [1025,256] fp32

  char* w8 = (char*)d_ws;
  const size_t MB = 1048576;
  const dim3 blk(256), vblk(1024);

  if (ws_size >= 127 * MB) {
    // ---- wide path: level-1 gemm + 6 LDS-free bf16 levels + fused tail
    unsigned short* T2   = (unsigned short*)(w8);             // 64 MiB span-2  (512)
    unsigned short* Qb   = (unsigned short*)(w8 + 64 * MB);   // 32 MiB span-4  (256)
    unsigned short* Q2   = (unsigned short*)(w8 + 96 * MB);   // 16 MiB span-8  (128)
    unsigned short* Q4   = (unsigned short*)(w8 + 112 * MB);  //  8 MiB span-16 (64)
    unsigned short* Rm   = (unsigned short*)(w8 + 120 * MB);  //  4 MiB span-32 (32)
    unsigned short* S64  = (unsigned short*)(w8 + 124 * MB);  //  2 MiB span-64 (16)
    unsigned short* S128 = (unsigned short*)(w8 + 126 * MB);  //  1 MiB span-128 (8)
    gemm_mfma<<<dim3(8192), blk, 0, stream>>>(m, nullptr, 2, 0, m, nullptr, 2, 1, T2, 1);
    gemm_bt<<<dim3(4096), blk, 0, stream>>>(T2,  Qb,   1);
    gemm_bt<<<dim3(2048), blk, 0, stream>>>(Qb,  Q2,   1);
    gemm_bt<<<dim3(1024), blk, 0, stream>>>(Q2,  Q4,   1);
    gemm_bt<<<dim3(512),  blk, 0, stream>>>(Q4,  Rm,   1);
    gemm_bt<<<dim3(256),  blk, 0, stream>>>(Rm,  S64,  1);
    gemm_bt<<<dim3(128),  blk, 0, stream>>>(S64, S128, 0);
    tail_fused<<<dim3(256), vblk, 0, stream>>>(x, S128, S64, Rm, Q4, Q2, Qb, m, out, 1);
  } else if (ws_size >= 67108864) {
    // ---- narrow path (half-split tree), all row-major (flags 0)
    unsigned short* buf0 = (unsigned short*)(w8);
    unsigned short* Qb   = (unsigned short*)(w8 + 33554432);  // span-4, 256 mats
    unsigned short* Q2   = (unsigned short*)(w8);             // 16 MiB span-8
    unsigned short* Q4   = (unsigned short*)(w8 + 16777216);  //  8 MiB span-16
    unsigned short* Rm   = (unsigned short*)(w8 + 25165824);  //  4 MiB span-32
    unsigned short* S64  = (unsigned short*)(w8 + 29360128);  //  2 MiB span-64
    unsigned short* S128 = (unsigned short*)(w8 + 31457280);  //  1 MiB span-128
    gemm_mfma<<<dim3(4096), blk, 0, stream>>>(m, nullptr, 2, 0, m, nullptr, 2, 1, buf0, 0);
    gemm_mfma<<<dim3(2048), blk, 0, stream>>>(nullptr, buf0, 2, 0, nullptr, buf0, 2, 1, Qb, 0);
    gemm_mfma<<<dim3(4096), blk, 0, stream>>>(m + 512L * DD, nullptr, 2, 0,
                                              m + 512L * DD, nullptr, 2, 1, buf0, 0);
    gemm_mfma<<<dim3(2048), blk, 0, stream>>>(nullptr, buf0, 2, 0, nullptr, buf0, 2, 1,
                                              Qb + 128L * DD, 0);
    gemm_mfma<<<dim3(2048), blk, 0, stream>>>(nullptr, Qb, 2, 0, nullptr, Qb, 2, 1, Q2, 0);
    gemm_mfma<<<dim3(1024), blk, 0, stream>>>(nullptr, Q2, 2, 0, nullptr, Q2, 2, 1, Q4, 0);
    gemm_mfma<<<dim3(512),  blk, 0, stream>>>(nullptr, Q4, 2, 0, nullptr, Q4, 2, 1, Rm, 0);
    gemm_mfma<<<dim3(256),  blk, 0, stream>>>(nullptr, Rm, 2, 0, nullptr, Rm, 2, 1, S64, 0);
    gemm_mfma<<<dim3(128),  blk, 0, stream>>>(nullptr, S64, 2, 0, nullptr, S64, 2, 1, S128, 0);
    tail_fused<<<dim3(256), vblk, 0, stream>>>(x, S128, S64, Rm, Q4, Q2, Qb, m, out, 0);
  } else {
    fallback_seq<<<dim3(1), blk, 0, stream>>>(x, m, out);
  }
}

// Round 9
// 565.701 us; speedup vs baseline: 1.1491x; 1.1491x over previous
//
#include <hip/hip_runtime.h>
#include <hip/hip_bf16.h>

// ============================================================================
// Hybrid matrix prefix scan:  res[k] = x @ (m_0 ... m_{k-1}),  N=1024, D=256.
// Deviation form everywhere: store P - I in bf16; combine is exact:
//   dev(XY) = devX + devY + devX@devY.
// Round 12: exact 565.5us R7 source + ONE surgical fix.
//   R8 counters exposed level-1: VGPR_Count=48 (vs ~100 live needed),
//   MfmaUtil 4%, 160us, all pipes idle -> compiler SINKS the A-fragment
//   loads into the MFMA loop (re-issued global loads serialize every MFMA).
//   Fix: asm volatile("" :: "v"(areg[kt])) keep-alives placed right BEFORE
//   __syncthreads() -- after B-staging loads issue (MLP preserved), forcing
//   areg materialized + live across the barrier so the MFMA loop reads
//   registers, not global memory. Zero math change.
// ============================================================================

#define D 256
#define DD 65536

typedef __attribute__((ext_vector_type(8))) short short8;
typedef __attribute__((ext_vector_type(4))) float f4;

__device__ __forceinline__ float bf2f(unsigned short u) {
  return __uint_as_float(((unsigned)u) << 16);
}
__device__ __forceinline__ unsigned short f2bf(float f) {
  __hip_bfloat16 h = __float2bfloat16(f);
  unsigned short u;
  __builtin_memcpy(&u, &h, 2);
  return u;
}
__device__ __forceinline__ unsigned f2bf2(float lo, float hi) {
  __hip_bfloat162 h = __float22bfloat162_rn(make_float2(lo, hi));
  unsigned u;
  __builtin_memcpy(&u, &h, 4);
  return u;
}
// fragment-order slot lane index: frag reads lane-contiguous b128.
#define LSWZ(i15, lq) (((((i15) & 15)) + ((lq) << 4)) ^ (lq))

// out[mat] = devA + devB + devA@devB (bf16 dev out), MFMA 16x16x32 bf16.
// 64x64 tile/block (16 blocks/mat), 4 waves. B staged full-K in LDS (32 KiB);
// A fragments live in registers. Block swizzle: xcd = bx&7; all 16 tiles of a
// mat on the same XCD (requires gridDim/16 divisible by 8).
__global__ __launch_bounds__(256, 4) void gemm_mfma(
    const float* __restrict__ aF, const unsigned short* __restrict__ aBf,
    long aMul, long aOff,
    const float* __restrict__ bF, const unsigned short* __restrict__ bBf,
    long bMul, long bOff,
    unsigned short* __restrict__ out)
{
  __shared__ __attribute__((aligned(16))) unsigned short Bs[16384]; // 32 KiB

  const int  bx  = blockIdx.x;
  const int  nmb = ((int)gridDim.x) >> 4;         // mats this dispatch (mult of 8)
  const int  xcd = bx & 7, q = bx >> 3;
  const long mat = (long)(xcd * (nmb >> 3)) + (q >> 4);
  const int  tile = q & 15;
  const int  m0 = (tile >> 2) << 6, n0 = (tile & 3) << 6;
  const long aBase = (mat * aMul + aOff) * (long)DD;
  const long bBase = (mat * bMul + bOff) * (long)DD;
  const int t = threadIdx.x;
  const int w = t >> 6, l = t & 63, lm = l & 15, lq4 = l >> 4;
  const int lswz = l ^ lq4;

  // ---- A fragments straight to registers.
  // Lane l of wave w feeds MFMA row R = m0+16w+(l&15), k = 32kt + 8*lq4 + j.
  const int R = m0 + (w << 4) + lm;
  short8 areg[8];
  if (aF) {
    const float* ap = aF + aBase + (long)R * D + (lq4 << 3);
#pragma unroll
    for (int kt = 0; kt < 8; ++kt) {
      float4 v0 = *(const float4*)(ap + (kt << 5));
      float4 v1 = *(const float4*)(ap + (kt << 5) + 4);
      // diag fixup: row R's diagonal col R lies in this 8-k strip iff
      // (R>>3) == 4*kt + lq4; then the component is j = R & 7.
      if ((R >> 3) == (kt << 2) + lq4) {
        const int j = R & 7;
        if      (j == 0) v0.x -= 1.f;
        else if (j == 1) v0.y -= 1.f;
        else if (j == 2) v0.z -= 1.f;
        else if (j == 3) v0.w -= 1.f;
        else if (j == 4) v1.x -= 1.f;
        else if (j == 5) v1.y -= 1.f;
        else if (j == 6) v1.z -= 1.f;
        else             v1.w -= 1.f;
      }
      union { short8 v8; unsigned u[4]; } ou;
      ou.u[0] = f2bf2(v0.x, v0.y);
      ou.u[1] = f2bf2(v0.z, v0.w);
      ou.u[2] = f2bf2(v1.x, v1.y);
      ou.u[3] = f2bf2(v1.z, v1.w);
      areg[kt] = ou.v8;
    }
  } else {
    const unsigned short* ap = aBf + aBase + (long)R * D + (lq4 << 3);
#pragma unroll
    for (int kt = 0; kt < 8; ++kt)
      areg[kt] = *(const short8*)(ap + (kt << 5));
  }

  // ---- stage B cols [n0,n0+64) x k[0,256) (register transpose into LDS)
  {
    const int n4 = (t & 15) << 2;
    const int kb0 = (t >> 4) << 3;
    const int gn = n0 + n4;
#pragma unroll
    for (int kp = 0; kp < 2; ++kp) {
      const int k8 = kb0 + (kp << 7);
      const int lq = (k8 >> 3) & 3, kt = k8 >> 5;
      if (bF) {
        // two-pass staging (va[2]/vb[2]): low VGPR pressure, no spill at 128.
        unsigned tmpu[4][4];
        const int rel = gn - k8;
#pragma unroll
        for (int h = 0; h < 2; ++h) {
          float4 va[2], vb[2];
#pragma unroll
          for (int p2 = 0; p2 < 2; ++p2) {
            va[p2] = *(const float4*)(bF + bBase + (long)(k8 + 4 * h + 2 * p2) * D + gn);
            vb[p2] = *(const float4*)(bF + bBase + (long)(k8 + 4 * h + 2 * p2 + 1) * D + gn);
          }
          // cols [gn,gn+4) have diag rows [gn,gn+4); they fall in this
          // 4-row half iff rel == 4h (gn,k8 4-/8-aligned).
          if (rel == 4 * h) {
            va[0].x -= 1.f; vb[0].y -= 1.f; va[1].z -= 1.f; vb[1].w -= 1.f;
          }
          tmpu[0][2 * h + 0] = f2bf2(va[0].x, vb[0].x);
          tmpu[0][2 * h + 1] = f2bf2(va[1].x, vb[1].x);
          tmpu[1][2 * h + 0] = f2bf2(va[0].y, vb[0].y);
          tmpu[1][2 * h + 1] = f2bf2(va[1].y, vb[1].y);
          tmpu[2][2 * h + 0] = f2bf2(va[0].z, vb[0].z);
          tmpu[2][2 * h + 1] = f2bf2(va[1].z, vb[1].z);
          tmpu[3][2 * h + 0] = f2bf2(va[0].w, vb[0].w);
          tmpu[3][2 * h + 1] = f2bf2(va[1].w, vb[1].w);
        }
#pragma unroll
        for (int jj = 0; jj < 4; ++jj) {
          const int n = n4 + jj;
          const int slot = (((n >> 4) << 3) + kt) * 64 + LSWZ(n, lq);
          uint4 st = { tmpu[jj][0], tmpu[jj][1], tmpu[jj][2], tmpu[jj][3] };
          *(uint4*)&Bs[slot << 3] = st;
        }
      } else {
        __attribute__((aligned(16))) unsigned short tmp[4][8];
#pragma unroll
        for (int kk = 0; kk < 8; ++kk) {
          const ushort4 v = *(const ushort4*)(bBf + bBase + (long)(k8 + kk) * D + gn);
          tmp[0][kk] = v.x; tmp[1][kk] = v.y; tmp[2][kk] = v.z; tmp[3][kk] = v.w;
        }
#pragma unroll
        for (int jj = 0; jj < 4; ++jj) {
          const int n = n4 + jj;
          const int slot = (((n >> 4) << 3) + kt) * 64 + LSWZ(n, lq);
          *(uint4*)&Bs[slot << 3] = *(const uint4*)&tmp[jj][0];
        }
      }
    }
  }
  // ---- force areg residency HERE (after all staging loads issued, before
  // the barrier): prevents the scheduler from sinking the A-frag loads into
  // the MFMA loop (R8 evidence: VGPR=48, MfmaUtil 4%, 160us level-1).
#pragma unroll
  for (int kt = 0; kt < 8; ++kt)
    asm volatile("" :: "v"(areg[kt]));
  __syncthreads();

  // ---- MFMA: A from registers, B frags lane-contiguous from LDS (32 b128)
  f4 acc[4] = {{0.f,0.f,0.f,0.f},{0.f,0.f,0.f,0.f},
               {0.f,0.f,0.f,0.f},{0.f,0.f,0.f,0.f}};
#pragma unroll
  for (int kt = 0; kt < 8; ++kt) {
#pragma unroll
    for (int f = 0; f < 4; ++f) {
      const short8 b = *(const short8*)&Bs[((((f << 3) + kt) << 6) + lswz) << 3];
      acc[f] = __builtin_amdgcn_mfma_f32_16x16x32_bf16(areg[kt], b, acc[f], 0, 0, 0);
    }
  }

  // ---- epilogue: s = acc + devA (global re-read, L2-hot) + devB (LDS)
#pragma unroll
  for (int f = 0; f < 4; ++f) {
    const int gj_l = (f << 4) + lm;
    const int gj   = n0 + gj_l;                   // A's k/col index
#pragma unroll
    for (int r = 0; r < 4; ++r) {
      const int gi_l = (w << 4) + (lq4 << 2) + r; // local row
      const int giG  = m0 + gi_l;                 // B's k index
      float da;
      if (aF)
        da = aF[aBase + (long)giG * D + gj] - ((giG == gj) ? 1.f : 0.f);
      else
        da = bf2f(aBf[aBase + (long)giG * D + gj]);
      const int lqB  = (giG >> 3) & 3;
      const int slotB = (((gj_l >> 4) << 3) + (giG >> 5)) * 64 + LSWZ(gj_l, lqB);
      const float db = bf2f(Bs[(slotB << 3) + (giG & 7)]);
      acc[f][r] += da + db;
    }
  }
  __syncthreads();                                // all Bs reads done

  // ---- C restage (pitch 66: conflict-free b16 writes) then coalesced store
  unsigned short* Cs = Bs;                        // reuse (4224 shorts)
#pragma unroll
  for (int f = 0; f < 4; ++f)
#pragma unroll
    for (int r = 0; r < 4; ++r)
      Cs[((w << 4) + (lq4 << 2) + r) * 66 + (f << 4) + lm] = f2bf(acc[f][r]);
  __syncthreads();
  {
    const int row = t >> 2, c0g = (t & 3) << 4;   // 16 shorts per thread
    const unsigned int* Cw = (const unsigned int*)Cs;
    const int wb = row * 33 + ((t & 3) << 3);
    unsigned int wbuf[8];
#pragma unroll
    for (int i = 0; i < 8; ++i) wbuf[i] = Cw[wb + i];
    unsigned short* og = out + mat * (long)DD + (long)(m0 + row) * D + n0 + c0g;
    uint4 o0 = { wbuf[0], wbuf[1], wbuf[2], wbuf[3] };
    uint4 o1 = { wbuf[4], wbuf[5], wbuf[6], wbuf[7] };
    *(uint4*)og = o0;
    *((uint4*)og + 1) = o1;
  }
}

// v = v + v @ dev(M), vectorized: 64 col-groups (4 cols) x 16 k-groups (16 i).
__device__ __forceinline__ void apply_bf16(const unsigned short* __restrict__ Mb,
                                           float* v, float (*ps)[D],
                                           int t, int col4, int q) {
  const unsigned short* Mp = Mb + (long)(q * 16) * D + col4;
  float a0 = 0.f, a1 = 0.f, a2 = 0.f, a3 = 0.f;
#pragma unroll
  for (int i = 0; i < 16; ++i) {
    const ushort4 u = *(const ushort4*)(Mp + (long)i * D);
    const float vi = v[q * 16 + i];
    a0 += vi * bf2f(u.x); a1 += vi * bf2f(u.y);
    a2 += vi * bf2f(u.z); a3 += vi * bf2f(u.w);
  }
  *(float4*)&ps[q][col4] = make_float4(a0, a1, a2, a3);
  __syncthreads();
  if (t < D) {
    float s = 0.f;
#pragma unroll
    for (int j = 0; j < 16; ++j) s += ps[j][t];
    v[t] += s;
  }
  __syncthreads();
}

// ONE kernel for the whole tail. WG c targets prefix length L = 4c:
// greedy span descent (128*,64,32,16,8,4), then exact fp32 bottom mat-vecs
// over m emitting out rows L..L+3 (c=255 also emits row 1024).
__global__ __launch_bounds__(1024) void tail_fused(
    const float* __restrict__ x,
    const unsigned short* __restrict__ sp128, const unsigned short* __restrict__ sp64,
    const unsigned short* __restrict__ sp32,  const unsigned short* __restrict__ sp16,
    const unsigned short* __restrict__ sp8,   const unsigned short* __restrict__ sp4,
    const float* __restrict__ m, float* __restrict__ out)
{
  __shared__ float v[D];
  __shared__ float ps[16][D];
  const int c = blockIdx.x, t = threadIdx.x;
  const int col4 = (t & 63) << 2, q = t >> 6;     // 64 col-groups x 16 k-groups
  if (t < D) v[t] = x[t];
  __syncthreads();
  const int L = c << 2;

  int pos = 0;
#pragma unroll 1
  while (pos + 128 <= L) { apply_bf16(sp128 + (long)(pos >> 7) * DD, v, ps, t, col4, q); pos += 128; }
  if (pos + 64 <= L) { apply_bf16(sp64 + (long)(pos >> 6) * DD, v, ps, t, col4, q); pos += 64; }
  if (pos + 32 <= L) { apply_bf16(sp32 + (long)(pos >> 5) * DD, v, ps, t, col4, q); pos += 32; }
  if (pos + 16 <= L) { apply_bf16(sp16 + (long)(pos >> 4) * DD, v, ps, t, col4, q); pos += 16; }
  if (pos + 8 <= L)  { apply_bf16(sp8  + (long)(pos >> 3) * DD, v, ps, t, col4, q); pos += 8; }
  if (pos + 4 <= L)  { apply_bf16(sp4  + (long)(pos >> 2) * DD, v, ps, t, col4, q); pos += 4; }

  // bottom: emit rows with exact fp32 mat-vecs over m (float4 loads)
  if (t < D) out[(long)L * D + t] = v[t];
  const int steps = (c == 255) ? 4 : 3;
#pragma unroll 1
  for (int s = 0; s < steps; ++s) {
    const float* Mp = m + (long)(L + s) * DD + (long)(q * 16) * D + col4;
    float a0 = 0.f, a1 = 0.f, a2 = 0.f, a3 = 0.f;
#pragma unroll
    for (int i = 0; i < 16; ++i) {
      const float4 u = *(const float4*)(Mp + (long)i * D);
      const float vi = v[q * 16 + i];
      a0 += vi * u.x; a1 += vi * u.y; a2 += vi * u.z; a3 += vi * u.w;
    }
    *(float4*)&ps[q][col4] = make_float4(a0, a1, a2, a3);
    __syncthreads();
    if (t < D) {
      float s2 = 0.f;
#pragma unroll
      for (int j = 0; j < 16; ++j) s2 += ps[j][t];
      v[t] = s2;
      out[(long)(L + s + 1) * D + t] = s2;
    }
    __syncthreads();
  }
}

// correctness-only fallback if ws is too small: fully sequential chain
__global__ __launch_bounds__(256) void fallback_seq(
    const float* __restrict__ x, const float* __restrict__ m,
    float* __restrict__ out)
{
  __shared__ float v[D];
  const int t = threadIdx.x;
  v[t] = x[t];
  __syncthreads();
  for (int k = 0; k < 1024; ++k) {
    out[(long)k * D + t] = v[t];
    const float* M = m + (long)k * DD;
    float acc = 0.f;
    for (int i = 0; i < D; ++i) acc += v[i] * M[(long)i * D + t];
    __syncthreads();
    v[t] = acc;
    __syncthreads();
  }
  out[(long)1024 * D + t] = v[t];
}

extern "C" void kernel_launch(void* const* d_in, const int* in_sizes, int n_in,
                              void* d_out, int out_size, void* d_ws, size_t ws_size,
                              hipStream_t stream) {
  const float* x = (const float*)d_in[0];   // [1,256] fp32
  const float* m = (const float*)d_in[1];   // [1024,256,256] fp32
  float* out = (float*)d_out;               // [1025,256] fp32

  char* w8 = (char*)d_ws;
  const size_t MB = 1048576;
  const dim3 blk(256), vblk(1024);

  if (ws_size >= 127 * MB) {
    // ---- wide path: full-width tree, one launch per level (7 gemms + tail)
    unsigned short* T2   = (unsigned short*)(w8);             // 64 MiB span-2  (512)
    unsigned short* Qb   = (unsigned short*)(w8 + 64 * MB);   // 32 MiB span-4  (256)
    unsigned short* Q2   = (unsigned short*)(w8 + 96 * MB);   // 16 MiB span-8  (128)
    unsigned short* Q4   = (unsigned short*)(w8 + 112 * MB);  //  8 MiB span-16 (64)
    unsigned short* Rm   = (unsigned short*)(w8 + 120 * MB);  //  4 MiB span-32 (32)
    unsigned short* S64  = (unsigned short*)(w8 + 124 * MB);  //  2 MiB span-64 (16)
    unsigned short* S128 = (unsigned short*)(w8 + 126 * MB);  //  1 MiB span-128 (8)
    gemm_mfma<<<dim3(8192), blk, 0, stream>>>(m, nullptr, 2, 0, m, nullptr, 2, 1, T2);
    gemm_mfma<<<dim3(4096), blk, 0, stream>>>(nullptr, T2, 2, 0, nullptr, T2, 2, 1, Qb);
    gemm_mfma<<<dim3(2048), blk, 0, stream>>>(nullptr, Qb, 2, 0, nullptr, Qb, 2, 1, Q2);
    gemm_mfma<<<dim3(1024), blk, 0, stream>>>(nullptr, Q2, 2, 0, nullptr, Q2, 2, 1, Q4);
    gemm_mfma<<<dim3(512),  blk, 0, stream>>>(nullptr, Q4, 2, 0, nullptr, Q4, 2, 1, Rm);
    gemm_mfma<<<dim3(256),  blk, 0, stream>>>(nullptr, Rm, 2, 0, nullptr, Rm, 2, 1, S64);
    gemm_mfma<<<dim3(128),  blk, 0, stream>>>(nullptr, S64, 2, 0, nullptr, S64, 2, 1, S128);
    tail_fused<<<dim3(256), vblk, 0, stream>>>(x, S128, S64, Rm, Q4, Q2, Qb, m, out);
  } else if (ws_size >= 67108864) {
    // ---- narrow path (half-split tree), fused tail
    unsigned short* buf0 = (unsigned short*)(w8);
    unsigned short* Qb   = (unsigned short*)(w8 + 33554432);  // span-4, 256 mats
    unsigned short* Q2   = (unsigned short*)(w8);             // 16 MiB span-8
    unsigned short* Q4   = (unsigned short*)(w8 + 16777216);  //  8 MiB span-16
    unsigned short* Rm   = (unsigned short*)(w8 + 25165824);  //  4 MiB span-32
    unsigned short* S64  = (unsigned short*)(w8 + 29360128);  //  2 MiB span-64
    unsigned short* S128 = (unsigned short*)(w8 + 31457280);  //  1 MiB span-128
    gemm_mfma<<<dim3(4096), blk, 0, stream>>>(m, nullptr, 2, 0, m, nullptr, 2, 1, buf0);
    gemm_mfma<<<dim3(2048), blk, 0, stream>>>(nullptr, buf0, 2, 0, nullptr, buf0, 2, 1, Qb);
    gemm_mfma<<<dim3(4096), blk, 0, stream>>>(m + 512L * DD, nullptr, 2, 0,
                                              m + 512L * DD, nullptr, 2, 1, buf0);
    gemm_mfma<<<dim3(2048), blk, 0, stream>>>(nullptr, buf0, 2, 0, nullptr, buf0, 2, 1,
                                              Qb + 128L * DD);
    gemm_mfma<<<dim3(2048), blk, 0, stream>>>(nullptr, Qb, 2, 0, nullptr, Qb, 2, 1, Q2);
    gemm_mfma<<<dim3(1024), blk, 0, stream>>>(nullptr, Q2, 2, 0, nullptr, Q2, 2, 1, Q4);
    gemm_mfma<<<dim3(512),  blk, 0, stream>>>(nullptr, Q4, 2, 0, nullptr, Q4, 2, 1, Rm);
    gemm_mfma<<<dim3(256),  blk, 0, stream>>>(nullptr, Rm, 2, 0, nullptr, Rm, 2, 1, S64);
    gemm_mfma<<<dim3(128),  blk, 0, stream>>>(nullptr, S64, 2, 0, nullptr, S64, 2, 1, S128);
    tail_fused<<<dim3(256), vblk, 0, stream>>>(x, S128, S64, Rm, Q4, Q2, Qb, m, out);
  } else {
    fallback_seq<<<dim3(1), blk, 0, stream>>>(x, m, out);
  }
}